// Round 10
// baseline (2133.484 us; speedup 1.0000x reference)
//
#include <hip/hip_runtime.h>

#define N_NODES 100000
#define N_EDGES 1600000
#define NBUCK   ((N_NODES + 127) / 128)   // 782 buckets of 128 rows
#define BCAP    4096                      // fixed bucket capacity (mean 2048, std 45)
// IN_DIM=512, HID_DIM=128, OUT_DIM=64

typedef __attribute__((ext_vector_type(8))) short bf16x8;
typedef __attribute__((ext_vector_type(4))) float f32x4;

__device__ __forceinline__ unsigned short f2bf(float f) {
    unsigned int u = __builtin_bit_cast(unsigned int, f);
    u = (u + 0x7FFFu + ((u >> 16) & 1u)) >> 16;   // RNE
    return (unsigned short)u;
}
__device__ __forceinline__ float bfu2f(unsigned short u) {
    return __builtin_bit_cast(float, (unsigned int)u << 16);
}

// Raw barrier: waits LDS ops only — global prefetch loads stay in flight.
__device__ __forceinline__ void block_barrier() {
    asm volatile("s_waitcnt lgkmcnt(0)" ::: "memory");
    __builtin_amdgcn_sched_barrier(0);
    __builtin_amdgcn_s_barrier();
    __builtin_amdgcn_sched_barrier(0);
}

// ---------------------------------------------------------------------------
// prep: W0->W0t bf16 transposed, W1->W1t bf16 transposed,
// bcursor[b] = b*BCAP (fixed bucket bases).
// ---------------------------------------------------------------------------
__global__ __launch_bounds__(256) void prep_kernel(const float* __restrict__ W0,
                                                   const float* __restrict__ W1,
                                                   unsigned short* __restrict__ W0t,
                                                   unsigned short* __restrict__ W1t,
                                                   int* __restrict__ bcursor) {
    const int i = blockIdx.x * 256 + threadIdx.x;
    if (i < 512 * 128) {
        const int k = i / 128, c = i % 128;
        W0t[c * 512 + k] = f2bf(W0[i]);
    }
    const int j = i - 512 * 128;
    if (j >= 0 && j < 128 * 64) {
        const int k = j / 64, c = j % 64;
        W1t[c * 128 + k] = f2bf(W1[j]);
    }
    const int z = i - (512 * 128 + 128 * 64);
    if (z >= 0 && z < NBUCK) bcursor[z] = z * BCAP;
}

// ---------------------------------------------------------------------------
// Pipelined MFMA GEMM: C_bf16[N,M] = A_f32[N,K] @ W (Wt[M][K] bf16).
// 4 waves (2m x 2n), tile 64 x M, BK=32. Depth-2 prefetch in NAMED regs;
// double-buffered LDS; raw barriers.
// ---------------------------------------------------------------------------
template<int K, int M>
__global__ __launch_bounds__(256) void mfma_gemm_kernel(const float* __restrict__ A,
                                                        const unsigned short* __restrict__ Wt,
                                                        unsigned short* __restrict__ C, int N) {
    constexpr int NSTEP = K / 32;
    constexpr int NFR   = M / 32;
    constexpr int NB    = M / 64;
    constexpr int LDT   = 40;       // LDS row stride (ushorts)

    __shared__ __align__(16) unsigned short As[2][64 * LDT];
    __shared__ __align__(16) unsigned short Bs[2][M * LDT];

    const int tid  = threadIdx.x;
    const int lane = tid & 63;
    const int wid  = tid >> 6;
    const int wm   = wid >> 1;
    const int wn   = wid & 1;
    const int brow = blockIdx.x * 64;

    const int ar0 = tid >> 3, akq = tid & 7;
    const int ar1 = ar0 + 32;
    const bool v0 = (brow + ar0) < N;
    const bool v1 = (brow + ar1) < N;
    const float* ap0 = A + (size_t)(brow + ar0) * K + akq * 4;
    const float* ap1 = A + (size_t)(brow + ar1) * K + akq * 4;
    const int br0 = tid >> 2, bkq = tid & 3;
    const unsigned short* bp0 = Wt + (size_t)br0 * K + bkq * 8;
    const unsigned short* bp1 = Wt + (size_t)(br0 + 64) * K + bkq * 8;

    float4 A0a, A0b, A1a, A1b;
    uint4  B0a, B0b, B1a, B1b;

    auto issue0 = [&](int t) {
        const int ko = t * 32;
        A0a = v0 ? *reinterpret_cast<const float4*>(ap0 + ko) : make_float4(0.f, 0.f, 0.f, 0.f);
        A0b = v1 ? *reinterpret_cast<const float4*>(ap1 + ko) : make_float4(0.f, 0.f, 0.f, 0.f);
        B0a = *reinterpret_cast<const uint4*>(bp0 + ko);
        if (NB == 2) B0b = *reinterpret_cast<const uint4*>(bp1 + ko);
    };
    auto issue1 = [&](int t) {
        const int ko = t * 32;
        A1a = v0 ? *reinterpret_cast<const float4*>(ap0 + ko) : make_float4(0.f, 0.f, 0.f, 0.f);
        A1b = v1 ? *reinterpret_cast<const float4*>(ap1 + ko) : make_float4(0.f, 0.f, 0.f, 0.f);
        B1a = *reinterpret_cast<const uint4*>(bp0 + ko);
        if (NB == 2) B1b = *reinterpret_cast<const uint4*>(bp1 + ko);
    };

    auto pack = [&](float4 v) -> uint2 {
        uint2 p;
        p.x = (unsigned int)f2bf(v.x) | ((unsigned int)f2bf(v.y) << 16);
        p.y = (unsigned int)f2bf(v.z) | ((unsigned int)f2bf(v.w) << 16);
        return p;
    };
    auto wlds0 = [&](int buf) {
        *reinterpret_cast<uint2*>(&As[buf][ar0 * LDT + akq * 4]) = pack(A0a);
        *reinterpret_cast<uint2*>(&As[buf][ar1 * LDT + akq * 4]) = pack(A0b);
        *reinterpret_cast<uint4*>(&Bs[buf][br0 * LDT + bkq * 8]) = B0a;
        if (NB == 2) *reinterpret_cast<uint4*>(&Bs[buf][(br0 + 64) * LDT + bkq * 8]) = B0b;
    };
    auto wlds1 = [&](int buf) {
        *reinterpret_cast<uint2*>(&As[buf][ar0 * LDT + akq * 4]) = pack(A1a);
        *reinterpret_cast<uint2*>(&As[buf][ar1 * LDT + akq * 4]) = pack(A1b);
        *reinterpret_cast<uint4*>(&Bs[buf][br0 * LDT + bkq * 8]) = B1a;
        if (NB == 2) *reinterpret_cast<uint4*>(&Bs[buf][(br0 + 64) * LDT + bkq * 8]) = B1b;
    };

    f32x4 acc[2][NFR];
#pragma unroll
    for (int m = 0; m < 2; ++m)
#pragma unroll
        for (int n = 0; n < NFR; ++n) acc[m][n] = (f32x4){0.f, 0.f, 0.f, 0.f};

    const int afo = (wm * 32 + (lane & 15)) * LDT + (lane >> 4) * 8;
    const int bfo = (wn * (M / 2) + (lane & 15)) * LDT + (lane >> 4) * 8;

    auto step = [&](int buf) {
        bf16x8 af[2], bfr[NFR];
#pragma unroll
        for (int m = 0; m < 2; ++m)
            af[m] = *reinterpret_cast<const bf16x8*>(&As[buf][afo + m * 16 * LDT]);
#pragma unroll
        for (int n = 0; n < NFR; ++n)
            bfr[n] = *reinterpret_cast<const bf16x8*>(&Bs[buf][bfo + n * 16 * LDT]);
#pragma unroll
        for (int m = 0; m < 2; ++m)
#pragma unroll
            for (int n = 0; n < NFR; ++n)
                acc[m][n] = __builtin_amdgcn_mfma_f32_16x16x32_bf16(af[m], bfr[n], acc[m][n], 0, 0, 0);
    };

    issue0(0);
    issue1(1);
    wlds0(0);
    block_barrier();

#pragma unroll
    for (int i = 0; i < NSTEP / 2; ++i) {
        const int t = 2 * i;
        if (t + 2 < NSTEP) issue0(t + 2);
        step(0);
        wlds1(1);
        block_barrier();
        if (t + 3 < NSTEP) issue1(t + 3);
        step(1);
        if (t + 2 < NSTEP) wlds0(0);
        block_barrier();
    }

    const int rb = brow + wm * 32 + ((lane >> 4) * 4);
    const int cb = wn * (M / 2) + (lane & 15);
#pragma unroll
    for (int m = 0; m < 2; ++m)
#pragma unroll
        for (int n = 0; n < NFR; ++n)
#pragma unroll
            for (int j = 0; j < 4; ++j) {
                const int r = rb + m * 16 + j;
                if (r < N) C[(size_t)r * M + cb + n * 16] = f2bf(acc[m][n][j]);
            }
}

// ---------------------------------------------------------------------------
// LDS-free GEMM2: sup1_bf16[N,64] = h_bf16[N,128] @ W1 (Wt[64][128] bf16).
// ---------------------------------------------------------------------------
__global__ __launch_bounds__(256) void gemm2_kernel(const unsigned short* __restrict__ Hb,
                                                    const unsigned short* __restrict__ Wt,
                                                    unsigned short* __restrict__ C) {
    const int gw = (blockIdx.x * 256 + threadIdx.x) >> 6;
    if (gw >= N_NODES / 16) return;
    const int lane = threadIdx.x & 63;
    const int rlo = lane & 15, khi = lane >> 4;
    const int rb = gw * 16;

    const unsigned short* wp = Wt + (size_t)rlo * 128 + khi * 8;
    bf16x8 b[4][4];
#pragma unroll
    for (int n = 0; n < 4; ++n)
#pragma unroll
        for (int t = 0; t < 4; ++t)
            b[n][t] = *reinterpret_cast<const bf16x8*>(wp + (size_t)n * 16 * 128 + t * 32);

    f32x4 acc[4];
#pragma unroll
    for (int n = 0; n < 4; ++n) acc[n] = (f32x4){0.f, 0.f, 0.f, 0.f};

    const unsigned short* hp = Hb + (size_t)(rb + rlo) * 128 + khi * 8;
#pragma unroll
    for (int t = 0; t < 4; ++t) {
        const bf16x8 af = *reinterpret_cast<const bf16x8*>(hp + t * 32);
#pragma unroll
        for (int n = 0; n < 4; ++n)
            acc[n] = __builtin_amdgcn_mfma_f32_16x16x32_bf16(af, b[n][t], acc[n], 0, 0, 0);
    }

#pragma unroll
    for (int n = 0; n < 4; ++n)
#pragma unroll
        for (int j = 0; j < 4; ++j)
            C[(size_t)(rb + khi * 4 + j) * 64 + n * 16 + rlo] = f2bf(acc[n][j]);
}

// ---------------------------------------------------------------------------
// Bucket append (block-aggregated): each block histograms its 4096 edges over
// the 782 buckets in LDS, reserves space with ONE global atomic per
// (block, nonzero bucket), then appends {col | rowlocal<<17, val} into the
// bucket's FIXED region [b*BCAP ...). No row_ptr / scan needed.
// ---------------------------------------------------------------------------
#define SCAT_CH 4096
__global__ __launch_bounds__(256) void scatter_bucket_kernel(const int* __restrict__ rows,
                                                             const int* __restrict__ cols,
                                                             const float* __restrict__ vals,
                                                             int* __restrict__ bcursor,
                                                             int2* __restrict__ tmp) {
    __shared__ int hist[NBUCK];   // counts, then global-base cursors
    const int tid = threadIdx.x;
    const int e0  = blockIdx.x * SCAT_CH;

    for (int b = tid; b < NBUCK; b += 256) hist[b] = 0;
    __syncthreads();

    // phase 1: block-local histogram
#pragma unroll
    for (int i = 0; i < SCAT_CH / 256; ++i) {
        const int e = e0 + i * 256 + tid;
        if (e < N_EDGES) atomicAdd(&hist[rows[e] >> 7], 1);
    }
    __syncthreads();

    // phase 2: reserve global region per bucket (one atomic per nonzero bucket)
    for (int b = tid; b < NBUCK; b += 256) {
        const int hcnt = hist[b];
        hist[b] = (hcnt > 0) ? atomicAdd(&bcursor[b], hcnt) : 0;
    }
    __syncthreads();

    // phase 3: append via LDS cursors (edge data L2-hot from phase 1)
#pragma unroll
    for (int i = 0; i < SCAT_CH / 256; ++i) {
        const int e = e0 + i * 256 + tid;
        if (e < N_EDGES) {
            const int r   = rows[e];
            const int pos = atomicAdd(&hist[r >> 7], 1);
            tmp[pos] = make_int2(cols[e] | ((r & 127) << 17), __float_as_int(vals[e]));
        }
    }
}

// ---------------------------------------------------------------------------
// Bucket SpMM with LDS fp32 accumulation: one 512-thread block per bucket
// (128 rows). Groups of GL lanes stream the bucket's edges (4-deep unroll,
// named regs), gather sup[col] (bf16x8/lane), and ds_add_f32 into the padded
// LDS tile. Flush adds bias (+relu/bf16 for layer 0). No row sorting needed.
// ---------------------------------------------------------------------------
template<int DIM, bool RELU_BF16_OUT>
__global__ __launch_bounds__(512) void spmm_lds_kernel(const int* __restrict__ bcursor,
                                                       const int2* __restrict__ tmp,
                                                       const unsigned short* __restrict__ sup,
                                                       const float* __restrict__ bias,
                                                       void* __restrict__ aggv) {
    constexpr int GL   = DIM / 8;        // lanes per edge-group (16 / 8)
    constexpr int NGRP = 512 / GL;       // concurrent edge-groups (32 / 64)
    constexpr int STR  = DIM + 4;        // padded LDS row stride (floats)

    __shared__ float acc[128 * STR];     // 67.6 KB (DIM=128) / 34.8 KB (DIM=64)

    const int b    = blockIdx.x;
    const int tid  = threadIdx.x;
    const int base = b * BCAP;
    const int cnt  = bcursor[b] - base;

    for (int i = tid; i < 128 * STR; i += 512) acc[i] = 0.f;
    __syncthreads();

    const int grp = tid / GL;
    const int sub = tid % GL;
    const int2* tp = tmp + base;

    int e = grp;
    // 4-deep unrolled main loop: 4 independent gather chains in flight
    for (; e + 3 * NGRP < cnt; e += 4 * NGRP) {
        const int2 w0 = tp[e];
        const int2 w1 = tp[e + NGRP];
        const int2 w2 = tp[e + 2 * NGRP];
        const int2 w3 = tp[e + 3 * NGRP];
        const bf16x8 s0 = *reinterpret_cast<const bf16x8*>(sup + (size_t)(w0.x & 0x1FFFF) * DIM + sub * 8);
        const bf16x8 s1 = *reinterpret_cast<const bf16x8*>(sup + (size_t)(w1.x & 0x1FFFF) * DIM + sub * 8);
        const bf16x8 s2 = *reinterpret_cast<const bf16x8*>(sup + (size_t)(w2.x & 0x1FFFF) * DIM + sub * 8);
        const bf16x8 s3 = *reinterpret_cast<const bf16x8*>(sup + (size_t)(w3.x & 0x1FFFF) * DIM + sub * 8);
        {
            const float v = __int_as_float(w0.y);
            float* dst = &acc[(((unsigned)w0.x) >> 17) * STR + sub * 8];
#pragma unroll
            for (int d = 0; d < 8; ++d) atomicAdd(&dst[d], v * bfu2f((unsigned short)s0[d]));
        }
        {
            const float v = __int_as_float(w1.y);
            float* dst = &acc[(((unsigned)w1.x) >> 17) * STR + sub * 8];
#pragma unroll
            for (int d = 0; d < 8; ++d) atomicAdd(&dst[d], v * bfu2f((unsigned short)s1[d]));
        }
        {
            const float v = __int_as_float(w2.y);
            float* dst = &acc[(((unsigned)w2.x) >> 17) * STR + sub * 8];
#pragma unroll
            for (int d = 0; d < 8; ++d) atomicAdd(&dst[d], v * bfu2f((unsigned short)s2[d]));
        }
        {
            const float v = __int_as_float(w3.y);
            float* dst = &acc[(((unsigned)w3.x) >> 17) * STR + sub * 8];
#pragma unroll
            for (int d = 0; d < 8; ++d) atomicAdd(&dst[d], v * bfu2f((unsigned short)s3[d]));
        }
    }
    for (; e < cnt; e += NGRP) {
        const int2 w = tp[e];
        const bf16x8 s = *reinterpret_cast<const bf16x8*>(sup + (size_t)(w.x & 0x1FFFF) * DIM + sub * 8);
        const float v = __int_as_float(w.y);
        float* dst = &acc[(((unsigned)w.x) >> 17) * STR + sub * 8];
#pragma unroll
        for (int d = 0; d < 8; ++d) atomicAdd(&dst[d], v * bfu2f((unsigned short)s[d]));
    }
    __syncthreads();

    // flush: out = acc + bias (+relu, bf16) per row
    const int rbase = b << 7;
    for (int i = tid; i < 128 * (DIM / 8); i += 512) {
        const int rl = i / (DIM / 8), sb = i % (DIM / 8);
        const int row = rbase + rl;
        if (row < N_NODES) {
            const float* src = &acc[rl * STR + sb * 8];
            float o[8];
#pragma unroll
            for (int d = 0; d < 8; ++d) o[d] = src[d] + bias[sb * 8 + d];
            if (RELU_BF16_OUT) {
                bf16x8 r;
#pragma unroll
                for (int d = 0; d < 8; ++d) r[d] = (short)f2bf(fmaxf(o[d], 0.f));
                *reinterpret_cast<bf16x8*>((unsigned short*)aggv + (size_t)row * DIM + sb * 8) = r;
            } else {
                float* dst = (float*)aggv + (size_t)row * DIM + sb * 8;
                *reinterpret_cast<float4*>(dst)     = make_float4(o[0], o[1], o[2], o[3]);
                *reinterpret_cast<float4*>(dst + 4) = make_float4(o[4], o[5], o[6], o[7]);
            }
        }
    }
}

// ---------------------------------------------------------------------------
extern "C" void kernel_launch(void* const* d_in, const int* in_sizes, int n_in,
                              void* d_out, int out_size, void* d_ws, size_t ws_size,
                              hipStream_t stream) {
    const float* x    = (const float*)d_in[0];
    const int*   rows = (const int*)d_in[1];
    const int*   cols = (const int*)d_in[2];
    const float* vals = (const float*)d_in[3];
    const float* W0   = (const float*)d_in[4];
    const float* b0   = (const float*)d_in[5];
    const float* W1   = (const float*)d_in[6];
    const float* b1   = (const float*)d_in[7];
    float*       out  = (float*)d_out;

    // Workspace carve (all chunks 16B-multiple)
    char* p = (char*)d_ws;
    unsigned short* sup0 = (unsigned short*)p;  p += (size_t)N_NODES * 128 * 2;  // 25.6 MB
    unsigned short* h    = (unsigned short*)p;  p += (size_t)N_NODES * 128 * 2;  // 25.6 MB
    unsigned short* sup1 = (unsigned short*)p;  p += (size_t)N_NODES * 64 * 2;   // 12.8 MB
    unsigned short* W0t  = (unsigned short*)p;  p += (size_t)512 * 128 * 2;
    unsigned short* W1t  = (unsigned short*)p;  p += (size_t)128 * 64 * 2;
    int*   bcursor  = (int*)p;                  p += (size_t)((NBUCK + 3) / 4) * 16;
    int2*  tmp      = (int2*)p;                 p += (size_t)NBUCK * BCAP * 8;   // 25.6 MB

    const int prep_blocks = (512 * 128 + 128 * 64 + NBUCK + 255) / 256;  // 292
    const int scat_blocks = (N_EDGES + SCAT_CH - 1) / SCAT_CH;           // 391
    const int gemm_blocks = (N_NODES + 63) / 64;                         // 1563
    const int gem2_blocks = (N_NODES / 16 + 3) / 4;                      // 1563

    // ---- prep (W converts + bucket cursor init) ----
    prep_kernel<<<prep_blocks, 256, 0, stream>>>(W0, W1, W0t, W1t, bcursor);

    // ---- bucket append (the only edge-reorg pass) ----
    scatter_bucket_kernel<<<scat_blocks, 256, 0, stream>>>(rows, cols, vals, bcursor, tmp);

    // ---- Layer 0 ----
    mfma_gemm_kernel<512, 128><<<gemm_blocks, 256, 0, stream>>>(x, W0t, sup0, N_NODES);
    spmm_lds_kernel<128, true><<<NBUCK, 512, 0, stream>>>(bcursor, tmp, sup0, b0, h);

    // ---- Layer 1 ----
    gemm2_kernel<<<gem2_blocks, 256, 0, stream>>>(h, W1t, sup1);
    spmm_lds_kernel<64, false><<<NBUCK, 512, 0, stream>>>(bcursor, tmp, sup1, b1, out);
}

// Round 11
// 249.001 us; speedup vs baseline: 8.5682x; 8.5682x over previous
//
#include <hip/hip_runtime.h>

#define N_NODES 100000
#define N_EDGES 1600000
#define NBUCK   ((N_NODES + 127) / 128)   // 782 buckets of 128 rows
#define BCAP    4096                      // fixed bucket capacity (mean 2048, std ~45)
// IN_DIM=512, HID_DIM=128, OUT_DIM=64

typedef __attribute__((ext_vector_type(8))) short bf16x8;
typedef __attribute__((ext_vector_type(4))) float f32x4;

__device__ __forceinline__ unsigned short f2bf(float f) {
    unsigned int u = __builtin_bit_cast(unsigned int, f);
    u = (u + 0x7FFFu + ((u >> 16) & 1u)) >> 16;   // RNE
    return (unsigned short)u;
}
__device__ __forceinline__ float bfu2f(unsigned short u) {
    return __builtin_bit_cast(float, (unsigned int)u << 16);
}

// Raw barrier: waits LDS ops only — global prefetch loads stay in flight.
__device__ __forceinline__ void block_barrier() {
    asm volatile("s_waitcnt lgkmcnt(0)" ::: "memory");
    __builtin_amdgcn_sched_barrier(0);
    __builtin_amdgcn_s_barrier();
    __builtin_amdgcn_sched_barrier(0);
}

// ---------------------------------------------------------------------------
// prep: W0->W0t bf16 transposed, W1->W1t bf16 transposed,
// bcursor[b] = b*BCAP (fixed bucket bases).
// ---------------------------------------------------------------------------
__global__ __launch_bounds__(256) void prep_kernel(const float* __restrict__ W0,
                                                   const float* __restrict__ W1,
                                                   unsigned short* __restrict__ W0t,
                                                   unsigned short* __restrict__ W1t,
                                                   int* __restrict__ bcursor) {
    const int i = blockIdx.x * 256 + threadIdx.x;
    if (i < 512 * 128) {
        const int k = i / 128, c = i % 128;
        W0t[c * 512 + k] = f2bf(W0[i]);
    }
    const int j = i - 512 * 128;
    if (j >= 0 && j < 128 * 64) {
        const int k = j / 64, c = j % 64;
        W1t[c * 128 + k] = f2bf(W1[j]);
    }
    const int z = i - (512 * 128 + 128 * 64);
    if (z >= 0 && z < NBUCK) bcursor[z] = z * BCAP;
}

// ---------------------------------------------------------------------------
// Pipelined MFMA GEMM: C_bf16[N,M] = A_f32[N,K] @ W (Wt[M][K] bf16).
// 4 waves (2m x 2n), tile 64 x M, BK=32. Depth-2 prefetch in NAMED regs;
// double-buffered LDS; raw barriers.
// ---------------------------------------------------------------------------
template<int K, int M>
__global__ __launch_bounds__(256) void mfma_gemm_kernel(const float* __restrict__ A,
                                                        const unsigned short* __restrict__ Wt,
                                                        unsigned short* __restrict__ C, int N) {
    constexpr int NSTEP = K / 32;
    constexpr int NFR   = M / 32;
    constexpr int NB    = M / 64;
    constexpr int LDT   = 40;       // LDS row stride (ushorts)

    __shared__ __align__(16) unsigned short As[2][64 * LDT];
    __shared__ __align__(16) unsigned short Bs[2][M * LDT];

    const int tid  = threadIdx.x;
    const int lane = tid & 63;
    const int wid  = tid >> 6;
    const int wm   = wid >> 1;
    const int wn   = wid & 1;
    const int brow = blockIdx.x * 64;

    const int ar0 = tid >> 3, akq = tid & 7;
    const int ar1 = ar0 + 32;
    const bool v0 = (brow + ar0) < N;
    const bool v1 = (brow + ar1) < N;
    const float* ap0 = A + (size_t)(brow + ar0) * K + akq * 4;
    const float* ap1 = A + (size_t)(brow + ar1) * K + akq * 4;
    const int br0 = tid >> 2, bkq = tid & 3;
    const unsigned short* bp0 = Wt + (size_t)br0 * K + bkq * 8;
    const unsigned short* bp1 = Wt + (size_t)(br0 + 64) * K + bkq * 8;

    float4 A0a, A0b, A1a, A1b;
    uint4  B0a, B0b, B1a, B1b;

    auto issue0 = [&](int t) {
        const int ko = t * 32;
        A0a = v0 ? *reinterpret_cast<const float4*>(ap0 + ko) : make_float4(0.f, 0.f, 0.f, 0.f);
        A0b = v1 ? *reinterpret_cast<const float4*>(ap1 + ko) : make_float4(0.f, 0.f, 0.f, 0.f);
        B0a = *reinterpret_cast<const uint4*>(bp0 + ko);
        if (NB == 2) B0b = *reinterpret_cast<const uint4*>(bp1 + ko);
    };
    auto issue1 = [&](int t) {
        const int ko = t * 32;
        A1a = v0 ? *reinterpret_cast<const float4*>(ap0 + ko) : make_float4(0.f, 0.f, 0.f, 0.f);
        A1b = v1 ? *reinterpret_cast<const float4*>(ap1 + ko) : make_float4(0.f, 0.f, 0.f, 0.f);
        B1a = *reinterpret_cast<const uint4*>(bp0 + ko);
        if (NB == 2) B1b = *reinterpret_cast<const uint4*>(bp1 + ko);
    };

    auto pack = [&](float4 v) -> uint2 {
        uint2 p;
        p.x = (unsigned int)f2bf(v.x) | ((unsigned int)f2bf(v.y) << 16);
        p.y = (unsigned int)f2bf(v.z) | ((unsigned int)f2bf(v.w) << 16);
        return p;
    };
    auto wlds0 = [&](int buf) {
        *reinterpret_cast<uint2*>(&As[buf][ar0 * LDT + akq * 4]) = pack(A0a);
        *reinterpret_cast<uint2*>(&As[buf][ar1 * LDT + akq * 4]) = pack(A0b);
        *reinterpret_cast<uint4*>(&Bs[buf][br0 * LDT + bkq * 8]) = B0a;
        if (NB == 2) *reinterpret_cast<uint4*>(&Bs[buf][(br0 + 64) * LDT + bkq * 8]) = B0b;
    };
    auto wlds1 = [&](int buf) {
        *reinterpret_cast<uint2*>(&As[buf][ar0 * LDT + akq * 4]) = pack(A1a);
        *reinterpret_cast<uint2*>(&As[buf][ar1 * LDT + akq * 4]) = pack(A1b);
        *reinterpret_cast<uint4*>(&Bs[buf][br0 * LDT + bkq * 8]) = B1a;
        if (NB == 2) *reinterpret_cast<uint4*>(&Bs[buf][(br0 + 64) * LDT + bkq * 8]) = B1b;
    };

    f32x4 acc[2][NFR];
#pragma unroll
    for (int m = 0; m < 2; ++m)
#pragma unroll
        for (int n = 0; n < NFR; ++n) acc[m][n] = (f32x4){0.f, 0.f, 0.f, 0.f};

    const int afo = (wm * 32 + (lane & 15)) * LDT + (lane >> 4) * 8;
    const int bfo = (wn * (M / 2) + (lane & 15)) * LDT + (lane >> 4) * 8;

    auto step = [&](int buf) {
        bf16x8 af[2], bfr[NFR];
#pragma unroll
        for (int m = 0; m < 2; ++m)
            af[m] = *reinterpret_cast<const bf16x8*>(&As[buf][afo + m * 16 * LDT]);
#pragma unroll
        for (int n = 0; n < NFR; ++n)
            bfr[n] = *reinterpret_cast<const bf16x8*>(&Bs[buf][bfo + n * 16 * LDT]);
#pragma unroll
        for (int m = 0; m < 2; ++m)
#pragma unroll
            for (int n = 0; n < NFR; ++n)
                acc[m][n] = __builtin_amdgcn_mfma_f32_16x16x32_bf16(af[m], bfr[n], acc[m][n], 0, 0, 0);
    };

    issue0(0);
    issue1(1);
    wlds0(0);
    block_barrier();

#pragma unroll
    for (int i = 0; i < NSTEP / 2; ++i) {
        const int t = 2 * i;
        if (t + 2 < NSTEP) issue0(t + 2);
        step(0);
        wlds1(1);
        block_barrier();
        if (t + 3 < NSTEP) issue1(t + 3);
        step(1);
        if (t + 2 < NSTEP) wlds0(0);
        block_barrier();
    }

    const int rb = brow + wm * 32 + ((lane >> 4) * 4);
    const int cb = wn * (M / 2) + (lane & 15);
#pragma unroll
    for (int m = 0; m < 2; ++m)
#pragma unroll
        for (int n = 0; n < NFR; ++n)
#pragma unroll
            for (int j = 0; j < 4; ++j) {
                const int r = rb + m * 16 + j;
                if (r < N) C[(size_t)r * M + cb + n * 16] = f2bf(acc[m][n][j]);
            }
}

// ---------------------------------------------------------------------------
// LDS-free GEMM2: sup1_bf16[N,64] = h_bf16[N,128] @ W1 (Wt[64][128] bf16).
// ---------------------------------------------------------------------------
__global__ __launch_bounds__(256) void gemm2_kernel(const unsigned short* __restrict__ Hb,
                                                    const unsigned short* __restrict__ Wt,
                                                    unsigned short* __restrict__ C) {
    const int gw = (blockIdx.x * 256 + threadIdx.x) >> 6;
    if (gw >= N_NODES / 16) return;
    const int lane = threadIdx.x & 63;
    const int rlo = lane & 15, khi = lane >> 4;
    const int rb = gw * 16;

    const unsigned short* wp = Wt + (size_t)rlo * 128 + khi * 8;
    bf16x8 b[4][4];
#pragma unroll
    for (int n = 0; n < 4; ++n)
#pragma unroll
        for (int t = 0; t < 4; ++t)
            b[n][t] = *reinterpret_cast<const bf16x8*>(wp + (size_t)n * 16 * 128 + t * 32);

    f32x4 acc[4];
#pragma unroll
    for (int n = 0; n < 4; ++n) acc[n] = (f32x4){0.f, 0.f, 0.f, 0.f};

    const unsigned short* hp = Hb + (size_t)(rb + rlo) * 128 + khi * 8;
#pragma unroll
    for (int t = 0; t < 4; ++t) {
        const bf16x8 af = *reinterpret_cast<const bf16x8*>(hp + t * 32);
#pragma unroll
        for (int n = 0; n < 4; ++n)
            acc[n] = __builtin_amdgcn_mfma_f32_16x16x32_bf16(af, b[n][t], acc[n], 0, 0, 0);
    }

#pragma unroll
    for (int n = 0; n < 4; ++n)
#pragma unroll
        for (int j = 0; j < 4; ++j)
            C[(size_t)(rb + khi * 4 + j) * 64 + n * 16 + rlo] = f2bf(acc[n][j]);
}

// ---------------------------------------------------------------------------
// Bucket append (block-aggregated): each block histograms its 4096 edges over
// the 782 buckets in LDS, reserves space with ONE global atomic per
// (block, nonzero bucket), then appends {col | rowlocal<<17, val} into the
// bucket's FIXED region [b*BCAP ...). No scan dependency.
// ---------------------------------------------------------------------------
#define SCAT_CH 4096
__global__ __launch_bounds__(256) void scatter_bucket_kernel(const int* __restrict__ rows,
                                                             const int* __restrict__ cols,
                                                             const float* __restrict__ vals,
                                                             int* __restrict__ bcursor,
                                                             int2* __restrict__ tmp) {
    __shared__ int hist[NBUCK];   // counts, then global-base cursors
    const int tid = threadIdx.x;
    const int e0  = blockIdx.x * SCAT_CH;

    for (int b = tid; b < NBUCK; b += 256) hist[b] = 0;
    __syncthreads();

    // phase 1: block-local histogram
#pragma unroll
    for (int i = 0; i < SCAT_CH / 256; ++i) {
        const int e = e0 + i * 256 + tid;
        if (e < N_EDGES) atomicAdd(&hist[rows[e] >> 7], 1);
    }
    __syncthreads();

    // phase 2: reserve global region per bucket (one atomic per nonzero bucket)
    for (int b = tid; b < NBUCK; b += 256) {
        const int hcnt = hist[b];
        hist[b] = (hcnt > 0) ? atomicAdd(&bcursor[b], hcnt) : 0;
    }
    __syncthreads();

    // phase 3: append via LDS cursors (edge data L2-hot from phase 1)
#pragma unroll
    for (int i = 0; i < SCAT_CH / 256; ++i) {
        const int e = e0 + i * 256 + tid;
        if (e < N_EDGES) {
            const int r   = rows[e];
            const int pos = atomicAdd(&hist[r >> 7], 1);
            tmp[pos] = make_int2(cols[e] | ((r & 127) << 17), __float_as_int(vals[e]));
        }
    }
}

// ---------------------------------------------------------------------------
// bucket_csr: one block per bucket. LDS int histogram of the bucket's edges,
// thread-0 scan of 128 counts -> row_range[row]={start,end}; then row-sort
// the bucket into meta via LDS int cursors. Replaces hist+scan+scatter_final.
// ---------------------------------------------------------------------------
__global__ __launch_bounds__(256) void bucket_csr_kernel(const int* __restrict__ bcursor,
                                                         const int2* __restrict__ tmp,
                                                         int2* __restrict__ meta,
                                                         int2* __restrict__ row_range) {
    __shared__ int cnt_sh[128];
    __shared__ int startsh[128];
    __shared__ int cur[128];
    const int b   = blockIdx.x;
    const int tid = threadIdx.x;
    const int base = b * BCAP;
    const int cnt  = bcursor[b] - base;

    if (tid < 128) cnt_sh[tid] = 0;
    __syncthreads();

    // histogram over local rows (int LDS atomics: native, fast)
    for (int j = tid; j < cnt; j += 256)
        atomicAdd(&cnt_sh[((unsigned int)tmp[base + j].x) >> 17], 1);
    __syncthreads();

    // serial scan of 128 counts (trivial vs ~2048-edge work)
    if (tid == 0) {
        int a = base;
        for (int i = 0; i < 128; ++i) { startsh[i] = a; a += cnt_sh[i]; }
    }
    __syncthreads();

    if (tid < 128) {
        cur[tid] = startsh[tid];
        const int row = (b << 7) + tid;
        if (row < N_NODES)
            row_range[row] = make_int2(startsh[tid], startsh[tid] + cnt_sh[tid]);
    }
    __syncthreads();

    // row-sort within bucket (writes land in the bucket's ~16KB window)
    for (int j = tid; j < cnt; j += 256) {
        const int2 w  = tmp[base + j];
        const int  rl = ((unsigned int)w.x) >> 17;
        const int  pos = atomicAdd(&cur[rl], 1);
        meta[pos] = make_int2(w.x & 0x1FFFF, w.y);
    }
}

// ---------------------------------------------------------------------------
// Atomic-free SpMM, one wave per row, NG edge-parallel groups, UN-deep unroll.
// Register accumulation + cross-group shuffle reduce (proven r9 structure).
// ---------------------------------------------------------------------------
template<int DIM, bool RELU_BF16_OUT>
__global__ __launch_bounds__(256) void spmm_kernel(const int2* __restrict__ row_range,
                                                   const int2* __restrict__ meta,
                                                   const unsigned short* __restrict__ sup,
                                                   const float* __restrict__ bias,
                                                   void* __restrict__ aggv) {
    const int wv = (blockIdx.x * 256 + threadIdx.x) >> 6;  // row id
    if (wv >= N_NODES) return;
    const int lane = threadIdx.x & 63;

    constexpr int GL = DIM / 8;              // lanes per group (16 / 8)
    constexpr int NG = 64 / GL;              // edge-parallel groups (4 / 8)
    constexpr int UN = (DIM == 128) ? 4 : 2; // unroll depth
    const int grp = lane / GL;
    const int sub = lane % GL;

    const int2 rr = row_range[wv];
    const int start = rr.x, end = rr.y;

    float a[8] = {0.f, 0.f, 0.f, 0.f, 0.f, 0.f, 0.f, 0.f};

    int j = start + grp;
    while (j + (UN - 1) * NG < end) {
        int2 e[UN];
#pragma unroll
        for (int u = 0; u < UN; ++u) e[u] = meta[j + u * NG];
        bf16x8 s[UN];
#pragma unroll
        for (int u = 0; u < UN; ++u)
            s[u] = *reinterpret_cast<const bf16x8*>(sup + (size_t)e[u].x * DIM + sub * 8);
#pragma unroll
        for (int u = 0; u < UN; ++u) {
            const float v = __int_as_float(e[u].y);
#pragma unroll
            for (int d = 0; d < 8; ++d)
                a[d] = fmaf(v, bfu2f((unsigned short)s[u][d]), a[d]);
        }
        j += UN * NG;
    }
    for (; j < end; j += NG) {
        const int2 e = meta[j];
        const bf16x8 s = *reinterpret_cast<const bf16x8*>(sup + (size_t)e.x * DIM + sub * 8);
        const float v = __int_as_float(e.y);
#pragma unroll
        for (int d = 0; d < 8; ++d)
            a[d] = fmaf(v, bfu2f((unsigned short)s[d]), a[d]);
    }

#pragma unroll
    for (int d = 0; d < 8; ++d) {
        if (GL == 8) a[d] += __shfl_xor(a[d], 8);
        a[d] += __shfl_xor(a[d], 16);
        a[d] += __shfl_xor(a[d], 32);
    }

    if (lane < GL) {
        const float4 b0 = *reinterpret_cast<const float4*>(bias + sub * 8);
        const float4 b1 = *reinterpret_cast<const float4*>(bias + sub * 8 + 4);
        float o[8];
        o[0] = a[0] + b0.x; o[1] = a[1] + b0.y; o[2] = a[2] + b0.z; o[3] = a[3] + b0.w;
        o[4] = a[4] + b1.x; o[5] = a[5] + b1.y; o[6] = a[6] + b1.z; o[7] = a[7] + b1.w;
        if (RELU_BF16_OUT) {
            unsigned short* h = (unsigned short*)aggv;
            bf16x8 r;
#pragma unroll
            for (int d = 0; d < 8; ++d) r[d] = (short)f2bf(fmaxf(o[d], 0.f));
            *reinterpret_cast<bf16x8*>(h + (size_t)wv * DIM + sub * 8) = r;
        } else {
            float* og = (float*)aggv;
            float* dst = og + (size_t)wv * DIM + sub * 8;
            *reinterpret_cast<float4*>(dst)     = make_float4(o[0], o[1], o[2], o[3]);
            *reinterpret_cast<float4*>(dst + 4) = make_float4(o[4], o[5], o[6], o[7]);
        }
    }
}

// ---------------------------------------------------------------------------
extern "C" void kernel_launch(void* const* d_in, const int* in_sizes, int n_in,
                              void* d_out, int out_size, void* d_ws, size_t ws_size,
                              hipStream_t stream) {
    const float* x    = (const float*)d_in[0];
    const int*   rows = (const int*)d_in[1];
    const int*   cols = (const int*)d_in[2];
    const float* vals = (const float*)d_in[3];
    const float* W0   = (const float*)d_in[4];
    const float* b0   = (const float*)d_in[5];
    const float* W1   = (const float*)d_in[6];
    const float* b1   = (const float*)d_in[7];
    float*       out  = (float*)d_out;

    // Workspace carve (all chunks 16B-multiple)
    char* p = (char*)d_ws;
    unsigned short* sup0 = (unsigned short*)p;  p += (size_t)N_NODES * 128 * 2;  // 25.6 MB
    unsigned short* h    = (unsigned short*)p;  p += (size_t)N_NODES * 128 * 2;  // 25.6 MB
    unsigned short* sup1 = (unsigned short*)p;  p += (size_t)N_NODES * 64 * 2;   // 12.8 MB
    unsigned short* W0t  = (unsigned short*)p;  p += (size_t)512 * 128 * 2;
    unsigned short* W1t  = (unsigned short*)p;  p += (size_t)128 * 64 * 2;
    int*   bcursor  = (int*)p;                  p += (size_t)((NBUCK + 3) / 4) * 16;
    int2*  row_range= (int2*)p;                 p += (size_t)N_NODES * 8;        // 0.8 MB
    int2*  tmp      = (int2*)p;                 p += (size_t)NBUCK * BCAP * 8;   // 25.6 MB
    int2*  meta     = (int2*)p;                 p += (size_t)NBUCK * BCAP * 8;   // 25.6 MB

    const int prep_blocks = (512 * 128 + 128 * 64 + NBUCK + 255) / 256;  // 292
    const int scat_blocks = (N_EDGES + SCAT_CH - 1) / SCAT_CH;           // 391
    const int gemm_blocks = (N_NODES + 63) / 64;                         // 1563
    const int gem2_blocks = (N_NODES / 16 + 3) / 4;                      // 1563
    const int spmm_blocks = (N_NODES * 64 + 255) / 256;                  // 25000

    // ---- prep (W converts + bucket cursor init) ----
    prep_kernel<<<prep_blocks, 256, 0, stream>>>(W0, W1, W0t, W1t, bcursor);

    // ---- edge reorg: bucket append + per-bucket CSR finish ----
    scatter_bucket_kernel<<<scat_blocks, 256, 0, stream>>>(rows, cols, vals, bcursor, tmp);
    bucket_csr_kernel<<<NBUCK, 256, 0, stream>>>(bcursor, tmp, meta, row_range);

    // ---- Layer 0 ----
    mfma_gemm_kernel<512, 128><<<gemm_blocks, 256, 0, stream>>>(x, W0t, sup0, N_NODES);
    spmm_kernel<128, true><<<spmm_blocks, 256, 0, stream>>>(row_range, meta, sup0, b0, h);

    // ---- Layer 1 ----
    gemm2_kernel<<<gem2_blocks, 256, 0, stream>>>(h, W1t, sup1);
    spmm_kernel<64, false><<<spmm_blocks, 256, 0, stream>>>(row_range, meta, sup1, b1, out);
}

// Round 12
// 248.992 us; speedup vs baseline: 8.5685x; 1.0000x over previous
//
#include <hip/hip_runtime.h>

#define N_NODES 100000
#define N_EDGES 1600000
#define NBUCK   ((N_NODES + 127) / 128)   // 782 buckets of 128 rows
#define BCAP    4096                      // fixed bucket capacity (mean 2048, std ~45)
// IN_DIM=512, HID_DIM=128, OUT_DIM=64

typedef __attribute__((ext_vector_type(8))) short bf16x8;
typedef __attribute__((ext_vector_type(4))) float f32x4;

__device__ __forceinline__ unsigned short f2bf(float f) {
    unsigned int u = __builtin_bit_cast(unsigned int, f);
    u = (u + 0x7FFFu + ((u >> 16) & 1u)) >> 16;   // RNE
    return (unsigned short)u;
}
__device__ __forceinline__ float bfu2f(unsigned short u) {
    return __builtin_bit_cast(float, (unsigned int)u << 16);
}
__device__ __forceinline__ uint2 packbf4(float4 v) {
    uint2 p;
    p.x = (unsigned int)f2bf(v.x) | ((unsigned int)f2bf(v.y) << 16);
    p.y = (unsigned int)f2bf(v.z) | ((unsigned int)f2bf(v.w) << 16);
    return p;
}

// Raw barrier: waits LDS ops only — global prefetch loads stay in flight.
__device__ __forceinline__ void block_barrier() {
    asm volatile("s_waitcnt lgkmcnt(0)" ::: "memory");
    __builtin_amdgcn_sched_barrier(0);
    __builtin_amdgcn_s_barrier();
    __builtin_amdgcn_sched_barrier(0);
}

// ---------------------------------------------------------------------------
// prep: W0->W0t bf16 transposed, W1->W1t bf16 transposed,
// bcursor[b] = b*BCAP (fixed bucket bases).
// ---------------------------------------------------------------------------
__global__ __launch_bounds__(256) void prep_kernel(const float* __restrict__ W0,
                                                   const float* __restrict__ W1,
                                                   unsigned short* __restrict__ W0t,
                                                   unsigned short* __restrict__ W1t,
                                                   int* __restrict__ bcursor) {
    const int i = blockIdx.x * 256 + threadIdx.x;
    if (i < 512 * 128) {
        const int k = i / 128, c = i % 128;
        W0t[c * 512 + k] = f2bf(W0[i]);
    }
    const int j = i - 512 * 128;
    if (j >= 0 && j < 128 * 64) {
        const int k = j / 64, c = j % 64;
        W1t[c * 128 + k] = f2bf(W1[j]);
    }
    const int z = i - (512 * 128 + 128 * 64);
    if (z >= 0 && z < NBUCK) bcursor[z] = z * BCAP;
}

// ---------------------------------------------------------------------------
// GEMM1 (depth-4 pipeline): sup0_bf16[N,128] = A_f32[N,512] @ W0 (Wt bf16).
// 4 waves (2m x 2n), tile 64x128, BK=32, 16 k-steps. FOUR named register
// prefetch slots (slot = t&3), double-buffered LDS, raw barriers. Loads are
// issued 4 k-steps ahead — ~2x the issue-to-consume slack of depth-2.
// ---------------------------------------------------------------------------
__global__ __launch_bounds__(256) void gemm1_kernel(const float* __restrict__ A,
                                                    const unsigned short* __restrict__ Wt,
                                                    unsigned short* __restrict__ C, int N) {
    constexpr int K   = 512;
    constexpr int M   = 128;
    constexpr int LDT = 40;       // LDS row stride (ushorts)

    __shared__ __align__(16) unsigned short As[2][64 * LDT];
    __shared__ __align__(16) unsigned short Bs[2][M * LDT];

    const int tid  = threadIdx.x;
    const int lane = tid & 63;
    const int wid  = tid >> 6;
    const int wm   = wid >> 1;
    const int wn   = wid & 1;
    const int brow = blockIdx.x * 64;

    const int ar0 = tid >> 3, akq = tid & 7;
    const int ar1 = ar0 + 32;
    const bool v0 = (brow + ar0) < N;
    const bool v1 = (brow + ar1) < N;
    const float* ap0 = A + (size_t)(brow + ar0) * K + akq * 4;
    const float* ap1 = A + (size_t)(brow + ar1) * K + akq * 4;
    const int br0 = tid >> 2, bkq = tid & 3;
    const unsigned short* bp0 = Wt + (size_t)br0 * K + bkq * 8;
    const unsigned short* bp1 = Wt + (size_t)(br0 + 64) * K + bkq * 8;

    // ---- 4 named prefetch slots ----
    float4 A0a, A0b, A1a, A1b, A2a, A2b, A3a, A3b;
    uint4  B0a, B0b, B1a, B1b, B2a, B2b, B3a, B3b;

#define ISSUE(s, t) do {                                                          \
        const int ko = (t) * 32;                                                  \
        A##s##a = v0 ? *reinterpret_cast<const float4*>(ap0 + ko)                 \
                     : make_float4(0.f, 0.f, 0.f, 0.f);                           \
        A##s##b = v1 ? *reinterpret_cast<const float4*>(ap1 + ko)                 \
                     : make_float4(0.f, 0.f, 0.f, 0.f);                           \
        B##s##a = *reinterpret_cast<const uint4*>(bp0 + ko);                      \
        B##s##b = *reinterpret_cast<const uint4*>(bp1 + ko);                      \
    } while (0)

#define WLDS(s, buf) do {                                                         \
        *reinterpret_cast<uint2*>(&As[buf][ar0 * LDT + akq * 4]) = packbf4(A##s##a); \
        *reinterpret_cast<uint2*>(&As[buf][ar1 * LDT + akq * 4]) = packbf4(A##s##b); \
        *reinterpret_cast<uint4*>(&Bs[buf][br0 * LDT + bkq * 8]) = B##s##a;          \
        *reinterpret_cast<uint4*>(&Bs[buf][(br0 + 64) * LDT + bkq * 8]) = B##s##b;   \
    } while (0)

    f32x4 acc[2][4];
#pragma unroll
    for (int m = 0; m < 2; ++m)
#pragma unroll
        for (int n = 0; n < 4; ++n) acc[m][n] = (f32x4){0.f, 0.f, 0.f, 0.f};

    const int afo = (wm * 32 + (lane & 15)) * LDT + (lane >> 4) * 8;
    const int bfo = (wn * 64 + (lane & 15)) * LDT + (lane >> 4) * 8;

    auto step = [&](int buf) {
        bf16x8 af[2], bfr[4];
#pragma unroll
        for (int m = 0; m < 2; ++m)
            af[m] = *reinterpret_cast<const bf16x8*>(&As[buf][afo + m * 16 * LDT]);
#pragma unroll
        for (int n = 0; n < 4; ++n)
            bfr[n] = *reinterpret_cast<const bf16x8*>(&Bs[buf][bfo + n * 16 * LDT]);
#pragma unroll
        for (int m = 0; m < 2; ++m)
#pragma unroll
            for (int n = 0; n < 4; ++n)
                acc[m][n] = __builtin_amdgcn_mfma_f32_16x16x32_bf16(af[m], bfr[n], acc[m][n], 0, 0, 0);
    };

    // prologue: tiles 0..3 in flight; tile 0 -> LDS0
    ISSUE(0, 0); ISSUE(1, 1); ISSUE(2, 2); ISSUE(3, 3);
    WLDS(0, 0);
    block_barrier();

    // 16 k-steps, 4 per outer iteration; tile t lives in slot t&3, LDS t&1.
#pragma unroll
    for (int i = 0; i < 4; ++i) {
        const int t = 4 * i;
        if (t + 4 < 16) ISSUE(0, t + 4);
        step(0);
        WLDS(1, 1);
        block_barrier();
        if (t + 5 < 16) ISSUE(1, t + 5);
        step(1);
        WLDS(2, 0);
        block_barrier();
        if (t + 6 < 16) ISSUE(2, t + 6);
        step(0);
        WLDS(3, 1);
        block_barrier();
        if (t + 7 < 16) ISSUE(3, t + 7);
        step(1);
        if (t + 4 < 16) WLDS(0, 0);
        block_barrier();
    }
#undef ISSUE
#undef WLDS

    const int rb = brow + wm * 32 + ((lane >> 4) * 4);
    const int cb = wn * 64 + (lane & 15);
#pragma unroll
    for (int m = 0; m < 2; ++m)
#pragma unroll
        for (int n = 0; n < 4; ++n)
#pragma unroll
            for (int j = 0; j < 4; ++j) {
                const int r = rb + m * 16 + j;
                if (r < N) C[(size_t)r * M + cb + n * 16] = f2bf(acc[m][n][j]);
            }
}

// ---------------------------------------------------------------------------
// LDS-free GEMM2: sup1_bf16[N,64] = h_bf16[N,128] @ W1 (Wt[64][128] bf16).
// ---------------------------------------------------------------------------
__global__ __launch_bounds__(256) void gemm2_kernel(const unsigned short* __restrict__ Hb,
                                                    const unsigned short* __restrict__ Wt,
                                                    unsigned short* __restrict__ C) {
    const int gw = (blockIdx.x * 256 + threadIdx.x) >> 6;
    if (gw >= N_NODES / 16) return;
    const int lane = threadIdx.x & 63;
    const int rlo = lane & 15, khi = lane >> 4;
    const int rb = gw * 16;

    const unsigned short* wp = Wt + (size_t)rlo * 128 + khi * 8;
    bf16x8 b[4][4];
#pragma unroll
    for (int n = 0; n < 4; ++n)
#pragma unroll
        for (int t = 0; t < 4; ++t)
            b[n][t] = *reinterpret_cast<const bf16x8*>(wp + (size_t)n * 16 * 128 + t * 32);

    f32x4 acc[4];
#pragma unroll
    for (int n = 0; n < 4; ++n) acc[n] = (f32x4){0.f, 0.f, 0.f, 0.f};

    const unsigned short* hp = Hb + (size_t)(rb + rlo) * 128 + khi * 8;
#pragma unroll
    for (int t = 0; t < 4; ++t) {
        const bf16x8 af = *reinterpret_cast<const bf16x8*>(hp + t * 32);
#pragma unroll
        for (int n = 0; n < 4; ++n)
            acc[n] = __builtin_amdgcn_mfma_f32_16x16x32_bf16(af, b[n][t], acc[n], 0, 0, 0);
    }

#pragma unroll
    for (int n = 0; n < 4; ++n)
#pragma unroll
        for (int j = 0; j < 4; ++j)
            C[(size_t)(rb + khi * 4 + j) * 64 + n * 16 + rlo] = f2bf(acc[n][j]);
}

// ---------------------------------------------------------------------------
// Bucket append (block-aggregated): LDS histogram -> one global atomic per
// (block, nonzero bucket) -> append into fixed region [b*BCAP ...).
// ---------------------------------------------------------------------------
#define SCAT_CH 4096
__global__ __launch_bounds__(256) void scatter_bucket_kernel(const int* __restrict__ rows,
                                                             const int* __restrict__ cols,
                                                             const float* __restrict__ vals,
                                                             int* __restrict__ bcursor,
                                                             int2* __restrict__ tmp) {
    __shared__ int hist[NBUCK];   // counts, then global-base cursors
    const int tid = threadIdx.x;
    const int e0  = blockIdx.x * SCAT_CH;

    for (int b = tid; b < NBUCK; b += 256) hist[b] = 0;
    __syncthreads();

#pragma unroll
    for (int i = 0; i < SCAT_CH / 256; ++i) {
        const int e = e0 + i * 256 + tid;
        if (e < N_EDGES) atomicAdd(&hist[rows[e] >> 7], 1);
    }
    __syncthreads();

    for (int b = tid; b < NBUCK; b += 256) {
        const int hcnt = hist[b];
        hist[b] = (hcnt > 0) ? atomicAdd(&bcursor[b], hcnt) : 0;
    }
    __syncthreads();

#pragma unroll
    for (int i = 0; i < SCAT_CH / 256; ++i) {
        const int e = e0 + i * 256 + tid;
        if (e < N_EDGES) {
            const int r   = rows[e];
            const int pos = atomicAdd(&hist[r >> 7], 1);
            tmp[pos] = make_int2(cols[e] | ((r & 127) << 17), __float_as_int(vals[e]));
        }
    }
}

// ---------------------------------------------------------------------------
// bucket_csr: one block per bucket. LDS int histogram, thread-0 scan,
// row_range emit, row-sort bucket into meta via LDS int cursors.
// ---------------------------------------------------------------------------
__global__ __launch_bounds__(256) void bucket_csr_kernel(const int* __restrict__ bcursor,
                                                         const int2* __restrict__ tmp,
                                                         int2* __restrict__ meta,
                                                         int2* __restrict__ row_range) {
    __shared__ int cnt_sh[128];
    __shared__ int startsh[128];
    __shared__ int cur[128];
    const int b   = blockIdx.x;
    const int tid = threadIdx.x;
    const int base = b * BCAP;
    const int cnt  = bcursor[b] - base;

    if (tid < 128) cnt_sh[tid] = 0;
    __syncthreads();

    for (int j = tid; j < cnt; j += 256)
        atomicAdd(&cnt_sh[((unsigned int)tmp[base + j].x) >> 17], 1);
    __syncthreads();

    if (tid == 0) {
        int a = base;
        for (int i = 0; i < 128; ++i) { startsh[i] = a; a += cnt_sh[i]; }
    }
    __syncthreads();

    if (tid < 128) {
        cur[tid] = startsh[tid];
        const int row = (b << 7) + tid;
        if (row < N_NODES)
            row_range[row] = make_int2(startsh[tid], startsh[tid] + cnt_sh[tid]);
    }
    __syncthreads();

    for (int j = tid; j < cnt; j += 256) {
        const int2 w  = tmp[base + j];
        const int  rl = ((unsigned int)w.x) >> 17;
        const int  pos = atomicAdd(&cur[rl], 1);
        meta[pos] = make_int2(w.x & 0x1FFFF, w.y);
    }
}

// ---------------------------------------------------------------------------
// Atomic-free SpMM, one wave per row, NG edge-parallel groups, UN=2 unroll
// (UN*NG = 8 <= mean degree 16, so the ILP path actually executes).
// ---------------------------------------------------------------------------
template<int DIM, bool RELU_BF16_OUT>
__global__ __launch_bounds__(256) void spmm_kernel(const int2* __restrict__ row_range,
                                                   const int2* __restrict__ meta,
                                                   const unsigned short* __restrict__ sup,
                                                   const float* __restrict__ bias,
                                                   void* __restrict__ aggv) {
    const int wv = (blockIdx.x * 256 + threadIdx.x) >> 6;  // row id
    if (wv >= N_NODES) return;
    const int lane = threadIdx.x & 63;

    constexpr int GL = DIM / 8;              // lanes per group (16 / 8)
    constexpr int NG = 64 / GL;              // edge-parallel groups (4 / 8)
    constexpr int UN = 2;                    // unroll depth
    const int grp = lane / GL;
    const int sub = lane % GL;

    const int2 rr = row_range[wv];
    const int start = rr.x, end = rr.y;

    float a[8] = {0.f, 0.f, 0.f, 0.f, 0.f, 0.f, 0.f, 0.f};

    int j = start + grp;
    while (j + (UN - 1) * NG < end) {
        int2 e[UN];
#pragma unroll
        for (int u = 0; u < UN; ++u) e[u] = meta[j + u * NG];
        bf16x8 s[UN];
#pragma unroll
        for (int u = 0; u < UN; ++u)
            s[u] = *reinterpret_cast<const bf16x8*>(sup + (size_t)e[u].x * DIM + sub * 8);
#pragma unroll
        for (int u = 0; u < UN; ++u) {
            const float v = __int_as_float(e[u].y);
#pragma unroll
            for (int d = 0; d < 8; ++d)
                a[d] = fmaf(v, bfu2f((unsigned short)s[u][d]), a[d]);
        }
        j += UN * NG;
    }
    for (; j < end; j += NG) {
        const int2 e = meta[j];
        const bf16x8 s = *reinterpret_cast<const bf16x8*>(sup + (size_t)e.x * DIM + sub * 8);
        const float v = __int_as_float(e.y);
#pragma unroll
        for (int d = 0; d < 8; ++d)
            a[d] = fmaf(v, bfu2f((unsigned short)s[d]), a[d]);
    }

#pragma unroll
    for (int d = 0; d < 8; ++d) {
        if (GL == 8) a[d] += __shfl_xor(a[d], 8);
        a[d] += __shfl_xor(a[d], 16);
        a[d] += __shfl_xor(a[d], 32);
    }

    if (lane < GL) {
        const float4 b0 = *reinterpret_cast<const float4*>(bias + sub * 8);
        const float4 b1 = *reinterpret_cast<const float4*>(bias + sub * 8 + 4);
        float o[8];
        o[0] = a[0] + b0.x; o[1] = a[1] + b0.y; o[2] = a[2] + b0.z; o[3] = a[3] + b0.w;
        o[4] = a[4] + b1.x; o[5] = a[5] + b1.y; o[6] = a[6] + b1.z; o[7] = a[7] + b1.w;
        if (RELU_BF16_OUT) {
            unsigned short* h = (unsigned short*)aggv;
            bf16x8 r;
#pragma unroll
            for (int d = 0; d < 8; ++d) r[d] = (short)f2bf(fmaxf(o[d], 0.f));
            *reinterpret_cast<bf16x8*>(h + (size_t)wv * DIM + sub * 8) = r;
        } else {
            float* og = (float*)aggv;
            float* dst = og + (size_t)wv * DIM + sub * 8;
            *reinterpret_cast<float4*>(dst)     = make_float4(o[0], o[1], o[2], o[3]);
            *reinterpret_cast<float4*>(dst + 4) = make_float4(o[4], o[5], o[6], o[7]);
        }
    }
}

// ---------------------------------------------------------------------------
extern "C" void kernel_launch(void* const* d_in, const int* in_sizes, int n_in,
                              void* d_out, int out_size, void* d_ws, size_t ws_size,
                              hipStream_t stream) {
    const float* x    = (const float*)d_in[0];
    const int*   rows = (const int*)d_in[1];
    const int*   cols = (const int*)d_in[2];
    const float* vals = (const float*)d_in[3];
    const float* W0   = (const float*)d_in[4];
    const float* b0   = (const float*)d_in[5];
    const float* W1   = (const float*)d_in[6];
    const float* b1   = (const float*)d_in[7];
    float*       out  = (float*)d_out;

    // Workspace carve (all chunks 16B-multiple)
    char* p = (char*)d_ws;
    unsigned short* sup0 = (unsigned short*)p;  p += (size_t)N_NODES * 128 * 2;  // 25.6 MB
    unsigned short* h    = (unsigned short*)p;  p += (size_t)N_NODES * 128 * 2;  // 25.6 MB
    unsigned short* sup1 = (unsigned short*)p;  p += (size_t)N_NODES * 64 * 2;   // 12.8 MB
    unsigned short* W0t  = (unsigned short*)p;  p += (size_t)512 * 128 * 2;
    unsigned short* W1t  = (unsigned short*)p;  p += (size_t)128 * 64 * 2;
    int*   bcursor  = (int*)p;                  p += (size_t)((NBUCK + 3) / 4) * 16;
    int2*  row_range= (int2*)p;                 p += (size_t)N_NODES * 8;        // 0.8 MB
    int2*  tmp      = (int2*)p;                 p += (size_t)NBUCK * BCAP * 8;   // 25.6 MB
    int2*  meta     = (int2*)p;                 p += (size_t)NBUCK * BCAP * 8;   // 25.6 MB

    const int prep_blocks = (512 * 128 + 128 * 64 + NBUCK + 255) / 256;  // 292
    const int scat_blocks = (N_EDGES + SCAT_CH - 1) / SCAT_CH;           // 391
    const int gemm_blocks = (N_NODES + 63) / 64;                         // 1563
    const int gem2_blocks = (N_NODES / 16 + 3) / 4;                      // 1563
    const int spmm_blocks = (N_NODES * 64 + 255) / 256;                  // 25000

    // ---- prep (W converts + bucket cursor init) ----
    prep_kernel<<<prep_blocks, 256, 0, stream>>>(W0, W1, W0t, W1t, bcursor);

    // ---- edge reorg: bucket append + per-bucket CSR finish ----
    scatter_bucket_kernel<<<scat_blocks, 256, 0, stream>>>(rows, cols, vals, bcursor, tmp);
    bucket_csr_kernel<<<NBUCK, 256, 0, stream>>>(bcursor, tmp, meta, row_range);

    // ---- Layer 0 ----
    gemm1_kernel<<<gemm_blocks, 256, 0, stream>>>(x, W0t, sup0, N_NODES);
    spmm_kernel<128, true><<<spmm_blocks, 256, 0, stream>>>(row_range, meta, sup0, b0, h);

    // ---- Layer 1 ----
    gemm2_kernel<<<gem2_blocks, 256, 0, stream>>>(h, W1t, sup1);
    spmm_kernel<64, false><<<spmm_blocks, 256, 0, stream>>>(row_range, meta, sup1, b1, out);
}